// Round 8
// baseline (46.704 us; speedup 1.0000x reference)
//
#include <hip/hip_runtime.h>

// out[b,p,ch] = mask[ch] ? x[b, perm[ch,p], ch] : x[b,p,ch]
// B=32, HW=3136, C=256, fp32. Compulsory ~206 MB -> ~33 us roofline.
#define HW      3136
#define NCH     256
#define LDP     (HW + 1)   // padded channel stride: 3137 % 32 == 1 -> bank=(c+r)%32
#define THREADS 1024

// stage: 2*HW float4s per step = 6272 -> 7 slots, slot 6 valid t<128
#define SSLOT 7
#define STAIL 128
// gather: HW pixels / 256 groups = 12.25 -> 13 slots, slot 12 valid t<256
#define GSLOT 13
#define GTAIL 256

// Relaxed barrier: LDS ordering only (lgkmcnt), leaves prefetch loads and
// store acks in flight (v7; neutral vs vmcnt-drain but provably safe here).
#define BAR_LGKM()                                         \
  do {                                                     \
    asm volatile("s_waitcnt lgkmcnt(0)" ::: "memory");     \
    __builtin_amdgcn_sched_barrier(0);                     \
    __builtin_amdgcn_s_barrier();                          \
    __builtin_amdgcn_sched_barrier(0);                     \
  } while (0)

// v8 = v7 pipeline, but grid 512 x 2 batches (was 256 x 4): halves per-block
// duration so block->CU assignment skew / duration variance quantizes at half
// the cost (Occupancy was 32% with a 1-block/CU grid = tail-diluted).
// sched_barrier(0) after ISSUE pins prefetch-load issue before the gather.
// XCD map: xcd owns chblks 4x..4x+3 (contiguous 32 ch = full 128B lines);
// its 400 KB perm slice stays L2-resident across both batches and blocks.
__global__ __launch_bounds__(THREADS) void jumble_v8_kernel(
    const float* __restrict__ x, const float* __restrict__ mask,
    const int* __restrict__ perm, float* __restrict__ out) {
  __shared__ float lds[8 * LDP];  // 100,384 B -> 1 block/CU, 16 waves

  const unsigned bid = blockIdx.x;
  const unsigned xcd = bid & 7u;
  const unsigned i = bid >> 3;                   // 0..63
  const unsigned chblk = xcd * 4u + (i & 3u);    // 0..31, 4 per XCD
  const unsigned b0 = (i >> 2) * 2u;             // batch pair: 0,2,..,30
  const unsigned ch0 = chblk * 8u;
  const unsigned t = threadIdx.x;

  // gather thread org: 4-lane groups own one pixel, 2ch per lane (32B chunks)
  const unsigned cp = t & 3u;
  const unsigned c0l = 2u * cp;
  const unsigned gp0 = t >> 2;

// ---- stage issue: paired lanes -> 32B chunks, 32 lines/wave ----
#define ISSUE(pf, bb)                                                      \
  {                                                                        \
    const float4* __restrict__ src =                                       \
        (const float4*)(x + (size_t)(bb) * (HW * NCH)) + (ch0 / 4);        \
    _Pragma("unroll") for (int j = 0; j < SSLOT; ++j) {                    \
      const unsigned f = t + (unsigned)j * THREADS;                        \
      if (j < SSLOT - 1 || t < STAIL)                                      \
        pf[j] = src[(size_t)(f >> 1) * (NCH / 4) + (f & 1u)];              \
    }                                                                      \
    __builtin_amdgcn_sched_barrier(0); /* pin: loads issue before gather */ \
  }

// ---- regs -> LDS, channel-major padded: bank=(c+p)%32, 2-way, free ----
#define DSWRITE(pf)                                                        \
  {                                                                        \
    _Pragma("unroll") for (int j = 0; j < SSLOT; ++j) {                    \
      const unsigned f = t + (unsigned)j * THREADS;                        \
      if (j < SSLOT - 1 || t < STAIL) {                                    \
        const unsigned p = f >> 1, cb = (f & 1u) * 4u;                     \
        lds[(cb + 0) * LDP + p] = pf[j].x;                                 \
        lds[(cb + 1) * LDP + p] = pf[j].y;                                 \
        lds[(cb + 2) * LDP + p] = pf[j].z;                                 \
        lds[(cb + 3) * LDP + p] = pf[j].w;                                 \
      }                                                                    \
    }                                                                      \
  }

// ---- gather from LDS + 32B-chunk stores (4-lane groups) ----
#define GATHER(bb)                                                         \
  {                                                                        \
    float* __restrict__ ob = out + (size_t)(bb) * (HW * NCH) + ch0;        \
    _Pragma("unroll") for (int k = 0; k < GSLOT; ++k) {                    \
      if (k < GSLOT - 1 || t < GTAIL) {                                    \
        const unsigned p = gp0 + (unsigned)k * 256u;                       \
        const unsigned rA = ridx[k] & 0xffffu;                             \
        const unsigned rB = ridx[k] >> 16;                                 \
        float2 v;                                                          \
        v.x = lds[(c0l + 0) * LDP + rA];                                   \
        v.y = lds[(c0l + 1) * LDP + rB];                                   \
        ((float2*)(ob + (size_t)p * NCH))[cp] = v;                         \
      }                                                                    \
    }                                                                      \
  }

  float4 pf[SSLOT];

  // prologue: x-loads for batch b0 in flight while perm indices load
  ISSUE(pf, b0 + 0)

  // ---- preload gather indices (packed 2x16b; reused across both batches) ----
  const int* __restrict__ prA = perm + (size_t)(ch0 + c0l) * HW;
  const int* __restrict__ prB = perm + (size_t)(ch0 + c0l + 1) * HW;
  const bool mA = mask[ch0 + c0l] != 0.0f;
  const bool mB = mask[ch0 + c0l + 1] != 0.0f;
  unsigned ridx[GSLOT];
#pragma unroll
  for (int k = 0; k < GSLOT; ++k) {
    if (k < GSLOT - 1 || t < GTAIL) {
      const int p = (int)(gp0 + (unsigned)k * 256u);
      const int rA = mA ? prA[p] : p;  // 64B-contiguous per 16-lane stream
      const int rB = mB ? prB[p] : p;
      ridx[k] = (unsigned)rA | ((unsigned)rB << 16);  // HW<4096 fits 16b
    }
  }

  DSWRITE(pf)  // counted vmcnt per pf element (no full drain)
  BAR_LGKM();

  // ---- steady state: issue(k+1) || gather(k), then regs->LDS ----
  ISSUE(pf, b0 + 1)
  GATHER(b0 + 0)
  BAR_LGKM();  // all waves' ds_reads consumed; prefetch stays in flight
  DSWRITE(pf)
  BAR_LGKM();  // ds_writes visible to all waves

  GATHER(b0 + 1)
}

extern "C" void kernel_launch(void* const* d_in, const int* in_sizes, int n_in,
                              void* d_out, int out_size, void* d_ws, size_t ws_size,
                              hipStream_t stream) {
  const float* x = (const float*)d_in[0];
  const float* mask = (const float*)d_in[1];
  const int* perm = (const int*)d_in[2];
  float* out = (float*)d_out;

  jumble_v8_kernel<<<512, THREADS, 0, stream>>>(x, mask, perm, out);
}

// Round 9
// 45.538 us; speedup vs baseline: 1.0256x; 1.0256x over previous
//
#include <hip/hip_runtime.h>

// out[b,p,ch] = mask[ch] ? x[b, perm[ch,p], ch] : x[b,p,ch]
// B=32, HW=3136, C=256, fp32. Compulsory ~206 MB -> ~33 us copy-roofline.
#define HW      3136
#define NCH     256
#define LDP     (HW + 1)   // padded channel stride: 3137 % 32 == 1 -> bank=(c+r)%32
#define THREADS 1024

// stage: 2*HW float4s per step = 6272 -> 7 slots, slot 6 valid t<128
#define SSLOT 7
#define STAIL 128
// gather: HW pixels / 256 groups = 12.25 -> 13 slots, slot 12 valid t<256
#define GSLOT 13
#define GTAIL 256

// Relaxed barrier: LDS ordering only (lgkmcnt); prefetch loads and store acks
// stay in flight across it (v7-proven safe: lgkmcnt(0) covers ds_read/ds_write
// completion; sched_barrier(0) fences DS ops from migrating across).
#define BAR_LGKM()                                         \
  do {                                                     \
    asm volatile("s_waitcnt lgkmcnt(0)" ::: "memory");     \
    __builtin_amdgcn_sched_barrier(0);                     \
    __builtin_amdgcn_s_barrier();                          \
    __builtin_amdgcn_sched_barrier(0);                     \
  } while (0)

// v9 = v6 pipeline + DEFERRED STORES. Per batch k (steady state):
//   ISSUE(k+1)          vmem loads -> pf regs (vmem pipe owned by prefetch)
//   GATHERR(k)          pure LDS: 26 ds_read -> g regs (no vmem competition)
//   BAR_LGKM            all waves' gathers done; prefetch stays in flight
//   STORE(k)+DSWRITE    stores (vmem) overlap pf->LDS (LDS pipe): the store
//                       wire drains through the whole phase, filling the
//                       barrier/DSWRITE gaps it previously idled through
//   BAR_LGKM            ds_writes visible
// Block = (8ch slab, 4 batches); grid 256, 1 block/CU (LDS 100 KB, 16 waves).
// perm indices loaded once, packed 2x16b, reused all 4 batches. XCD map: xcd
// owns chblks 4x..4x+3 (contiguous 32 ch = full 128B x/out lines per XCD);
// its 400 KB perm slice is L2-resident.
__global__ __launch_bounds__(THREADS) void jumble_v9_kernel(
    const float* __restrict__ x, const float* __restrict__ mask,
    const int* __restrict__ perm, float* __restrict__ out) {
  __shared__ float lds[8 * LDP];  // 100,384 B

  const unsigned bid = blockIdx.x;
  const unsigned xcd = bid & 7u;
  const unsigned i = bid >> 3;                   // 0..31
  const unsigned chblk = xcd * 4u + (i & 3u);    // 0..31, 4 per XCD
  const unsigned b0 = (i >> 2) * 4u;             // batch quad
  const unsigned ch0 = chblk * 8u;
  const unsigned t = threadIdx.x;

  // gather thread org: 4-lane groups own one pixel, 2ch per lane (32B chunks)
  const unsigned cp = t & 3u;
  const unsigned c0l = 2u * cp;
  const unsigned gp0 = t >> 2;

// ---- stage issue: paired lanes -> 32B chunks, 32 lines/wave ----
#define ISSUE(pf, bb)                                                      \
  {                                                                        \
    const float4* __restrict__ src =                                       \
        (const float4*)(x + (size_t)(bb) * (HW * NCH)) + (ch0 / 4);        \
    _Pragma("unroll") for (int j = 0; j < SSLOT; ++j) {                    \
      const unsigned f = t + (unsigned)j * THREADS;                        \
      if (j < SSLOT - 1 || t < STAIL)                                      \
        pf[j] = src[(size_t)(f >> 1) * (NCH / 4) + (f & 1u)];              \
    }                                                                      \
    __builtin_amdgcn_sched_barrier(0); /* pin: loads issue first */        \
  }

// ---- regs -> LDS, channel-major padded: bank=(c+p)%32, 2-way, free ----
#define DSWRITE(pf)                                                        \
  {                                                                        \
    _Pragma("unroll") for (int j = 0; j < SSLOT; ++j) {                    \
      const unsigned f = t + (unsigned)j * THREADS;                        \
      if (j < SSLOT - 1 || t < STAIL) {                                    \
        const unsigned p = f >> 1, cb = (f & 1u) * 4u;                     \
        lds[(cb + 0) * LDP + p] = pf[j].x;                                 \
        lds[(cb + 1) * LDP + p] = pf[j].y;                                 \
        lds[(cb + 2) * LDP + p] = pf[j].z;                                 \
        lds[(cb + 3) * LDP + p] = pf[j].w;                                 \
      }                                                                    \
    }                                                                      \
  }

// ---- pure-LDS gather into regs (no stores: vmem pipe left to prefetch) ----
#define GATHERR(g)                                                         \
  {                                                                        \
    _Pragma("unroll") for (int k = 0; k < GSLOT; ++k) {                    \
      if (k < GSLOT - 1 || t < GTAIL) {                                    \
        const unsigned rA = ridx[k] & 0xffffu;                             \
        const unsigned rB = ridx[k] >> 16;                                 \
        g[k].x = lds[(c0l + 0) * LDP + rA];                                \
        g[k].y = lds[(c0l + 1) * LDP + rB];                                \
      }                                                                    \
    }                                                                      \
  }

// ---- deferred stores: 32B chunks (4-lane groups), overlaps DSWRITE ----
#define STORE(g, bb)                                                       \
  {                                                                        \
    float* __restrict__ ob = out + (size_t)(bb) * (HW * NCH) + ch0;        \
    _Pragma("unroll") for (int k = 0; k < GSLOT; ++k) {                    \
      if (k < GSLOT - 1 || t < GTAIL) {                                    \
        const unsigned p = gp0 + (unsigned)k * 256u;                       \
        ((float2*)(ob + (size_t)p * NCH))[cp] = g[k];                      \
      }                                                                    \
    }                                                                      \
  }

  float4 pf[SSLOT];
  float2 g[GSLOT];

  // prologue: x-loads for batch b0 in flight while perm indices load
  ISSUE(pf, b0 + 0)

  // ---- preload gather indices once (packed 2x16b; reused all 4 batches) ----
  const int* __restrict__ prA = perm + (size_t)(ch0 + c0l) * HW;
  const int* __restrict__ prB = perm + (size_t)(ch0 + c0l + 1) * HW;
  const bool mA = mask[ch0 + c0l] != 0.0f;
  const bool mB = mask[ch0 + c0l + 1] != 0.0f;
  unsigned ridx[GSLOT];
#pragma unroll
  for (int k = 0; k < GSLOT; ++k) {
    if (k < GSLOT - 1 || t < GTAIL) {
      const int p = (int)(gp0 + (unsigned)k * 256u);
      const int rA = mA ? prA[p] : p;  // 64B-contiguous per 16-lane stream
      const int rB = mB ? prB[p] : p;
      ridx[k] = (unsigned)rA | ((unsigned)rB << 16);  // HW<4096 fits 16b
    }
  }

  DSWRITE(pf)  // counted vmcnt per pf element (no full drain)
  BAR_LGKM();

  // ---- batch 0 ----
  ISSUE(pf, b0 + 1)
  GATHERR(g)
  BAR_LGKM();
  STORE(g, b0 + 0)  // stores overlap next batch's DSWRITE
  DSWRITE(pf)
  BAR_LGKM();

  // ---- batch 1 ----
  ISSUE(pf, b0 + 2)
  GATHERR(g)
  BAR_LGKM();
  STORE(g, b0 + 1)
  DSWRITE(pf)
  BAR_LGKM();

  // ---- batch 2 ----
  ISSUE(pf, b0 + 3)
  GATHERR(g)
  BAR_LGKM();
  STORE(g, b0 + 2)
  DSWRITE(pf)
  BAR_LGKM();

  // ---- batch 3 (no prefetch) ----
  GATHERR(g)
  STORE(g, b0 + 3)
}

extern "C" void kernel_launch(void* const* d_in, const int* in_sizes, int n_in,
                              void* d_out, int out_size, void* d_ws, size_t ws_size,
                              hipStream_t stream) {
  const float* x = (const float*)d_in[0];
  const float* mask = (const float*)d_in[1];
  const int* perm = (const int*)d_in[2];
  float* out = (float*)d_out;

  jumble_v9_kernel<<<256, THREADS, 0, stream>>>(x, mask, perm, out);
}

// Round 10
// 44.494 us; speedup vs baseline: 1.0497x; 1.0235x over previous
//
#include <hip/hip_runtime.h>

// out[b,p,ch] = mask[ch] ? x[b, perm[ch,p], ch] : x[b,p,ch]
// B=32, HW=3136, C=256, fp32. Compulsory ~206 MB -> ~33 us copy-roofline.
// FINAL (v6, measured 44.16 us): LDS-staged gather, T14 async pipeline over
// 4 batches. Structural probes v7 (relaxed barriers), v8 (grid split),
// v9 (deferred stores) all neutral/negative -> this is the plateau.
#define HW      3136
#define NCH     256
#define LDP     (HW + 1)   // padded channel stride: 3137 % 32 == 1 -> bank=(c+r)%32
#define THREADS 1024

// stage: 2*HW float4s per step = 6272 -> 7 slots, slot 6 valid t<128
#define SSLOT 7
#define STAIL 128
// gather: HW pixels / 256 groups = 12.25 -> 13 slots, slot 12 valid t<256
#define GSLOT 13
#define GTAIL 256

// Block = (8-channel slab, 4 batches); grid 256 = 32 chblk x 8 batch-quads,
// 1 block/CU (LDS 100 KB). Steady state: issue x-loads(batch k+1) -> regs,
// gather+store(batch k) [hides the load latency], barrier, regs -> LDS,
// barrier. perm indices loaded ONCE, packed 2x16b in regs, reused 4 batches.
// XCD map: xcd owns chblks 4x..4x+3 = contiguous 32 ch = full 128B lines of
// x/out within one XCD; its 400 KB perm slice is L2-resident.
__global__ __launch_bounds__(THREADS) void jumble_v6_kernel(
    const float* __restrict__ x, const float* __restrict__ mask,
    const int* __restrict__ perm, float* __restrict__ out) {
  __shared__ float lds[8 * LDP];  // 100,384 B -> 1 block/CU, 16 waves

  const unsigned bid = blockIdx.x;
  const unsigned xcd = bid & 7u;
  const unsigned i = bid >> 3;                   // 0..31
  const unsigned chblk = xcd * 4u + (i & 3u);    // 0..31, 4 per XCD
  const unsigned b0 = (i >> 2) * 4u;             // batch quad
  const unsigned ch0 = chblk * 8u;
  const unsigned t = threadIdx.x;

  // gather thread org: 4-lane groups own one pixel, 2ch per lane (32B chunks)
  const unsigned cp = t & 3u;
  const unsigned c0l = 2u * cp;
  const unsigned gp0 = t >> 2;

// ---- stage issue: paired lanes -> 32B chunks, 32 lines/wave ----
#define ISSUE(pf, bb)                                                      \
  {                                                                        \
    const float4* __restrict__ src =                                       \
        (const float4*)(x + (size_t)(bb) * (HW * NCH)) + (ch0 / 4);        \
    _Pragma("unroll") for (int j = 0; j < SSLOT; ++j) {                    \
      const unsigned f = t + (unsigned)j * THREADS;                        \
      if (j < SSLOT - 1 || t < STAIL)                                      \
        pf[j] = src[(size_t)(f >> 1) * (NCH / 4) + (f & 1u)];              \
    }                                                                      \
  }

// ---- regs -> LDS, channel-major padded: bank=(c+p)%32, 2-way, free ----
#define DSWRITE(pf)                                                        \
  {                                                                        \
    _Pragma("unroll") for (int j = 0; j < SSLOT; ++j) {                    \
      const unsigned f = t + (unsigned)j * THREADS;                        \
      if (j < SSLOT - 1 || t < STAIL) {                                    \
        const unsigned p = f >> 1, cb = (f & 1u) * 4u;                     \
        lds[(cb + 0) * LDP + p] = pf[j].x;                                 \
        lds[(cb + 1) * LDP + p] = pf[j].y;                                 \
        lds[(cb + 2) * LDP + p] = pf[j].z;                                 \
        lds[(cb + 3) * LDP + p] = pf[j].w;                                 \
      }                                                                    \
    }                                                                      \
  }

// ---- gather from LDS + 32B-chunk stores (4-lane groups) ----
#define GATHER(bb)                                                         \
  {                                                                        \
    float* __restrict__ ob = out + (size_t)(bb) * (HW * NCH) + ch0;        \
    _Pragma("unroll") for (int k = 0; k < GSLOT; ++k) {                    \
      if (k < GSLOT - 1 || t < GTAIL) {                                    \
        const unsigned p = gp0 + (unsigned)k * 256u;                       \
        const unsigned rA = ridx[k] & 0xffffu;                             \
        const unsigned rB = ridx[k] >> 16;                                 \
        float2 v;                                                          \
        v.x = lds[(c0l + 0) * LDP + rA];                                   \
        v.y = lds[(c0l + 1) * LDP + rB];                                   \
        ((float2*)(ob + (size_t)p * NCH))[cp] = v;                         \
      }                                                                    \
    }                                                                      \
  }

  float4 pf[SSLOT];

  // prologue: x-loads for batch b0 in flight while perm indices load
  ISSUE(pf, b0 + 0)

  // ---- preload gather indices once (packed 2x16b; reused all 4 batches) ----
  const int* __restrict__ prA = perm + (size_t)(ch0 + c0l) * HW;
  const int* __restrict__ prB = perm + (size_t)(ch0 + c0l + 1) * HW;
  const bool mA = mask[ch0 + c0l] != 0.0f;
  const bool mB = mask[ch0 + c0l + 1] != 0.0f;
  unsigned ridx[GSLOT];
#pragma unroll
  for (int k = 0; k < GSLOT; ++k) {
    if (k < GSLOT - 1 || t < GTAIL) {
      const int p = (int)(gp0 + (unsigned)k * 256u);
      const int rA = mA ? prA[p] : p;  // 64B-contiguous per 16-lane stream
      const int rB = mB ? prB[p] : p;
      ridx[k] = (unsigned)rA | ((unsigned)rB << 16);  // HW<4096 fits 16b
    }
  }

  DSWRITE(pf)  // compiler inserts counted vmcnt for pf
  __syncthreads();

  // ---- steady state: issue(k+1) || gather(k), then regs->LDS ----
  ISSUE(pf, b0 + 1)
  GATHER(b0 + 0)
  __syncthreads();  // all waves done reading LDS
  DSWRITE(pf)
  __syncthreads();

  ISSUE(pf, b0 + 2)
  GATHER(b0 + 1)
  __syncthreads();
  DSWRITE(pf)
  __syncthreads();

  ISSUE(pf, b0 + 3)
  GATHER(b0 + 2)
  __syncthreads();
  DSWRITE(pf)
  __syncthreads();

  GATHER(b0 + 3)
}

extern "C" void kernel_launch(void* const* d_in, const int* in_sizes, int n_in,
                              void* d_out, int out_size, void* d_ws, size_t ws_size,
                              hipStream_t stream) {
  const float* x = (const float*)d_in[0];
  const float* mask = (const float*)d_in[1];
  const int* perm = (const int*)d_in[2];
  float* out = (float*)d_out;

  jumble_v6_kernel<<<256, THREADS, 0, stream>>>(x, mask, perm, out);
}